// Round 10
// baseline (254.408 us; speedup 1.0000x reference)
//
#include <hip/hip_runtime.h>
#include <cstdint>

// Problem constants (from reference)
constexpr int B_   = 4096;
constexpr int T_   = 512;
constexpr int DIN  = 10;
constexpr int H_   = 20;
constexpr int DOUT = 2;

constexpr int SPW = 3;            // samples per wave (3 x 20 = 60 active lanes)
constexpr int CH  = 2;            // timesteps per x-chunk (2*10 floats = 5 float4)
constexpr int XV  = CH * DIN / 4; // float4 prefetch regs per chunk

typedef float v2f __attribute__((ext_vector_type(2)));
typedef float v4f __attribute__((ext_vector_type(4)));

// Compiler-only memory fence: pins LDS op ordering for wave-synchronous
// exchange (single-wave workgroup; same-wave DS ops execute in order in HW).
#define CFENCE() asm volatile("" ::: "memory")

// One v_pk_fma_f32: two fp32 FMAs per instruction (gfx950 packed-FP32).
__device__ __forceinline__ v2f pkfma(v2f a, v2f b, v2f c) {
    return __builtin_elementwise_fma(a, b, c);
}
__device__ __forceinline__ v2f lohalf(v4f v) { return __builtin_shufflevector(v, v, 0, 1); }
__device__ __forceinline__ v2f hihalf(v4f v) { return __builtin_shufflevector(v, v, 2, 3); }

__device__ __forceinline__ float fast_tanh(float v) {
    // tanh(v) = 1 - 2/(exp2(2*log2e*v)+1): exact saturation at +/-inf
    float e = __builtin_amdgcn_exp2f(v * 2.885390082f);
    float r = __builtin_amdgcn_rcpf(e + 1.0f);
    return fmaf(-2.0f, r, 1.0f);
}

// De-skewed 2-layer RNN with ds_bpermute h1 all-gather:
//   h1(t) = tanh(xp[t] + wh0 . h1(t-1))        [h1(t-1) from prior gather]
//   gather: h1g[j] = bpermute(lane group_base+j, h1n)   -- no LDS write->read RT
//   h2(t) = tanh(bias1 + wi1 . h1(t) + wh1 . h2(t-1))   [h2 via LDS, latency-tolerant]
extern "C" __global__ void __launch_bounds__(64, 1)
rnn_bp(const float* __restrict__ x,
       const float* __restrict__ w_ih0, const float* __restrict__ w_hh0,
       const float* __restrict__ b_ih0, const float* __restrict__ b_hh0,
       const float* __restrict__ w_ih1, const float* __restrict__ w_hh1,
       const float* __restrict__ b_ih1, const float* __restrict__ b_hh1,
       const float* __restrict__ fc_w, const float* __restrict__ fc_b,
       float* __restrict__ out)
{
    const int lane = threadIdx.x;
    const int sl   = lane / H_;          // 0..2 active, 3 = idle lanes 60..63
    const int i    = lane - sl * H_;     // h-index 0..19
    const int samp = blockIdx.x * SPW + sl;
    const int sc   = (samp < B_) ? samp : (B_ - 1);   // clamped for safe loads
    const int slc  = (sl < SPW) ? sl : SPW;           // idle lanes -> spare row
    // bpermute byte base of this lane's group (idle lanes alias group 0 -> defined)
    const int gb   = ((sl < SPW) ? sl : 0) * H_ * 4;

    __shared__ __align__(16) float h2s[SPW + 1][H_];

    // ---- per-lane weight rows in registers (loop-invariant) ----
    v2f wi0p[DIN / 2];
    {
        const v2f* p = reinterpret_cast<const v2f*>(w_ih0 + i * DIN);
        #pragma unroll
        for (int k = 0; k < DIN / 2; ++k) wi0p[k] = p[k];
    }
    float wh0[H_], wi1[H_];          // scalar rows (h1 side is scalar-gathered)
    v2f wh1p[H_ / 2];                // h2 side keeps packed fp32
    {
        const v4f* p0 = reinterpret_cast<const v4f*>(w_hh0 + i * H_);
        const v4f* p1 = reinterpret_cast<const v4f*>(w_ih1 + i * H_);
        const v4f* p2 = reinterpret_cast<const v4f*>(w_hh1 + i * H_);
        #pragma unroll
        for (int k = 0; k < H_ / 4; ++k) {
            v4f a = p0[k]; wh0[4*k]=a.x; wh0[4*k+1]=a.y; wh0[4*k+2]=a.z; wh0[4*k+3]=a.w;
            v4f b = p1[k]; wi1[4*k]=b.x; wi1[4*k+1]=b.y; wi1[4*k+2]=b.z; wi1[4*k+3]=b.w;
            v4f c = p2[k]; wh1p[2*k] = lohalf(c); wh1p[2*k+1] = hihalf(c);
        }
    }
    const float bias0 = b_ih0[i] + b_hh0[i];
    const float bias1 = b_ih1[i] + b_hh1[i];

    // ---- state: h1g = gathered h1(t-1) (all 20 per lane), h2q = h2(t-1) ----
    float h1g[H_];
    v4f   h2q[H_ / 4];
    #pragma unroll
    for (int j = 0; j < H_; ++j) h1g[j] = 0.0f;
    #pragma unroll
    for (int k = 0; k < H_ / 4; ++k) h2q[k] = (v4f){0.f, 0.f, 0.f, 0.f};

    const v4f* xb = reinterpret_cast<const v4f*>(x + (size_t)sc * (T_ * DIN));

    // ---- prologue: prefetch chunk 0 ----
    v4f xv[XV];
    #pragma unroll
    for (int k = 0; k < XV; ++k) xv[k] = xb[k];

    auto getpair = [&](int p) -> v2f {
        v4f v = xv[p >> 1];
        return (p & 1) ? hihalf(v) : lohalf(v);
    };

    // consume xv -> xp for a chunk (5 pk_fma + add per step)
    auto consume_xp = [&](float (&xp)[CH]) {
        #pragma unroll
        for (int m = 0; m < CH; ++m) {
            v2f acc = (v2f){bias0, 0.f};
            #pragma unroll
            for (int q = 0; q < DIN / 2; ++q)
                acc = pkfma(getpair(m * (DIN / 2) + q), wi0p[q], acc);
            xp[m] = acc.x + acc.y;
        }
    };

    // one de-skewed step (reference order)
    auto full_step = [&](float xpm) {
        // ---- L0: h1(t) = tanh(xpm + wh0 . h1(t-1)) ----
        float a0 = xpm, a1 = 0.f, a2 = 0.f, a3 = 0.f;
        #pragma unroll
        for (int j = 0; j < H_; j += 4) {
            a0 = fmaf(h1g[j+0], wh0[j+0], a0);
            a1 = fmaf(h1g[j+1], wh0[j+1], a1);
            a2 = fmaf(h1g[j+2], wh0[j+2], a2);
            a3 = fmaf(h1g[j+3], wh0[j+3], a3);
        }
        float h1n = fast_tanh((a0 + a1) + (a2 + a3));

        // ---- h1 all-gather: register crossbar, no LDS write->read RT ----
        const int h1i = __float_as_int(h1n);
        #pragma unroll
        for (int j = 0; j < H_; ++j)
            h1g[j] = __int_as_float(__builtin_amdgcn_ds_bpermute(gb + 4 * j, h1i));

        // ---- L1: h2(t) = tanh(bias1 + wi1 . h1(t) + wh1 . h2(t-1)) ----
        float b0 = bias1, b1 = 0.f, b2 = 0.f, b3 = 0.f;
        #pragma unroll
        for (int j = 0; j < H_; j += 4) {
            b0 = fmaf(h1g[j+0], wi1[j+0], b0);
            b1 = fmaf(h1g[j+1], wi1[j+1], b1);
            b2 = fmaf(h1g[j+2], wi1[j+2], b2);
            b3 = fmaf(h1g[j+3], wi1[j+3], b3);
        }
        v2f bp0 = (v2f){0.f, 0.f}, bp1 = (v2f){0.f, 0.f};
        #pragma unroll
        for (int k = 0; k < H_ / 4; ++k) {
            bp0 = pkfma(lohalf(h2q[k]), wh1p[2*k],   bp0);
            bp1 = pkfma(hihalf(h2q[k]), wh1p[2*k+1], bp1);
        }
        v2f bs = bp0 + bp1;
        float h2n = fast_tanh(((b0 + b1) + (b2 + b3)) + (bs.x + bs.y));

        // ---- h2 exchange via LDS (consumed next step; RT fully hidden) ----
        CFENCE();
        h2s[slc][i] = h2n;
        CFENCE();
        #pragma unroll
        for (int k = 0; k < H_ / 4; ++k)
            h2q[k] = reinterpret_cast<const v4f*>(&h2s[slc][0])[k];
        CFENCE();
    };

    // ---- main loop: uniform, no peeling (h1g=h2q=0 gives exact t=0 semantics) ----
    for (int t0 = 0; t0 < T_; t0 += CH) {
        float xp[CH];
        consume_xp(xp);
        {
            const int t0n = (t0 + CH < T_) ? (t0 + CH) : 0;  // clamp, branchless
            #pragma unroll
            for (int k = 0; k < XV; ++k) xv[k] = xb[(t0n * DIN) / 4 + k];
        }
        #pragma unroll
        for (int m = 0; m < CH; ++m) full_step(xp[m]);
    }

    // ---- FC: lanes i<2 hold full h2(T-1) in h2q; out[samp][i] ----
    if (sl < SPW && samp < B_ && i < DOUT) {
        const v2f* fw = reinterpret_cast<const v2f*>(fc_w + i * H_);
        v2f acc = (v2f){fc_b[i], 0.f};
        #pragma unroll
        for (int k = 0; k < H_ / 4; ++k) {
            acc = pkfma(lohalf(h2q[k]), fw[2*k],   acc);
            acc = pkfma(hihalf(h2q[k]), fw[2*k+1], acc);
        }
        out[samp * DOUT + i] = acc.x + acc.y;
    }
}

extern "C" void kernel_launch(void* const* d_in, const int* in_sizes, int n_in,
                              void* d_out, int out_size, void* d_ws, size_t ws_size,
                              hipStream_t stream) {
    (void)in_sizes; (void)n_in; (void)d_ws; (void)ws_size; (void)out_size;
    const float* x     = (const float*)d_in[0];
    const float* w_ih0 = (const float*)d_in[1];
    const float* w_hh0 = (const float*)d_in[2];
    const float* b_ih0 = (const float*)d_in[3];
    const float* b_hh0 = (const float*)d_in[4];
    const float* w_ih1 = (const float*)d_in[5];
    const float* w_hh1 = (const float*)d_in[6];
    const float* b_ih1 = (const float*)d_in[7];
    const float* b_hh1 = (const float*)d_in[8];
    const float* fc_w  = (const float*)d_in[9];
    const float* fc_b  = (const float*)d_in[10];
    float* out = (float*)d_out;

    const int grid = (B_ + SPW - 1) / SPW;   // 1366 single-wave blocks
    hipLaunchKernelGGL(rnn_bp, dim3(grid), dim3(64), 0, stream,
                       x, w_ih0, w_hh0, b_ih0, b_hh0,
                       w_ih1, w_hh1, b_ih1, b_hh1, fc_w, fc_b, out);
}

// Round 11
// 145.227 us; speedup vs baseline: 1.7518x; 1.7518x over previous
//
#include <hip/hip_runtime.h>
#include <cstdint>

// Problem constants (from reference)
constexpr int B_   = 4096;
constexpr int T_   = 512;
constexpr int DIN  = 10;
constexpr int H_   = 20;
constexpr int DOUT = 2;

constexpr int SPW = 3;            // samples per wave (3 x 20 = 60 active lanes)
constexpr int CH  = 2;            // timesteps per x-chunk (2*10 floats = 5 float4)
constexpr int XV  = CH * DIN / 4; // float4 prefetch regs per chunk

typedef float v2f __attribute__((ext_vector_type(2)));
typedef float v4f __attribute__((ext_vector_type(4)));

// One v_pk_fma_f32: two fp32 FMAs per instruction (gfx950 packed-FP32).
__device__ __forceinline__ v2f pkfma(v2f a, v2f b, v2f c) {
    return __builtin_elementwise_fma(a, b, c);
}
__device__ __forceinline__ v2f lohalf(v4f v) { return __builtin_shufflevector(v, v, 0, 1); }
__device__ __forceinline__ v2f hihalf(v4f v) { return __builtin_shufflevector(v, v, 2, 3); }

__device__ __forceinline__ float fast_tanh(float v) {
    // tanh(v) = 1 - 2/(exp2(2*log2e*v)+1): exact saturation at +/-inf
    float e = __builtin_amdgcn_exp2f(v * 2.885390082f);
    float r = __builtin_amdgcn_rcpf(e + 1.0f);
    return fmaf(-2.0f, r, 1.0f);
}

// Skewed 2-layer RNN, issue-early/consume-late LDS exchange:
//   h1(tau)   = tanh(xp[tau] + wh0 . h1(tau-1))
//   [write h1; READ h1 back immediately -- read latency hides under L1]
//   h2(tau-1) = tanh(bias1 + wi1 . h1(tau-1) + wh1 . h2(tau-2))
//   [write h2; read h2 back -- latency hides under next step's L0]
// No asm memory fences: the exchange reads may-alias the same-array writes
// (runtime lane index), so the compiler cannot hoist reads above writes, and
// the wave-synchronous DS pipe executes them in order.
extern "C" __global__ void __launch_bounds__(64, 1)
rnn_pk2(const float* __restrict__ x,
        const float* __restrict__ w_ih0, const float* __restrict__ w_hh0,
        const float* __restrict__ b_ih0, const float* __restrict__ b_hh0,
        const float* __restrict__ w_ih1, const float* __restrict__ w_hh1,
        const float* __restrict__ b_ih1, const float* __restrict__ b_hh1,
        const float* __restrict__ fc_w, const float* __restrict__ fc_b,
        float* __restrict__ out)
{
    const int lane = threadIdx.x;
    const int sl   = lane / H_;          // 0..2 active, 3 = idle lanes 60..63
    const int i    = lane - sl * H_;     // h-index 0..19
    const int samp = blockIdx.x * SPW + sl;
    const int sc   = (samp < B_) ? samp : (B_ - 1);   // clamped for safe loads
    const int slc  = (sl < SPW) ? sl : SPW;           // idle lanes -> spare row

    __shared__ __align__(16) float h1s[SPW + 1][H_];
    __shared__ __align__(16) float h2s[SPW + 1][H_];

    // ---- per-lane weight rows as float2 pairs (loop-invariant) ----
    v2f wi0p[DIN / 2];
    {
        const v2f* p = reinterpret_cast<const v2f*>(w_ih0 + i * DIN);
        #pragma unroll
        for (int k = 0; k < DIN / 2; ++k) wi0p[k] = p[k];
    }
    v2f wh0p[H_ / 2], wi1p[H_ / 2], wh1p[H_ / 2];
    {
        const v4f* p0 = reinterpret_cast<const v4f*>(w_hh0 + i * H_);
        const v4f* p1 = reinterpret_cast<const v4f*>(w_ih1 + i * H_);
        const v4f* p2 = reinterpret_cast<const v4f*>(w_hh1 + i * H_);
        #pragma unroll
        for (int k = 0; k < H_ / 4; ++k) {
            v4f a = p0[k]; wh0p[2*k] = lohalf(a); wh0p[2*k+1] = hihalf(a);
            v4f b = p1[k]; wi1p[2*k] = lohalf(b); wi1p[2*k+1] = hihalf(b);
            v4f c = p2[k]; wh1p[2*k] = lohalf(c); wh1p[2*k+1] = hihalf(c);
        }
    }
    const float bias0 = b_ih0[i] + b_hh0[i];
    const float bias1 = b_ih1[i] + b_hh1[i];

    // ---- register state as pairs: h1p = h1(tau-1), h2p = h2(tau-2) ----
    v2f h1p[H_ / 2], h2p[H_ / 2];
    #pragma unroll
    for (int k = 0; k < H_ / 2; ++k) {
        h1p[k] = (v2f){0.f, 0.f};
        h2p[k] = (v2f){0.f, 0.f};
    }

    const v4f* xb = reinterpret_cast<const v4f*>(x + (size_t)sc * (T_ * DIN));

    // ---- prologue: prefetch chunk 0 ----
    v4f xv[XV];
    #pragma unroll
    for (int k = 0; k < XV; ++k) xv[k] = xb[k];

    auto getpair = [&](int p) -> v2f {
        v4f v = xv[p >> 1];
        return (p & 1) ? hihalf(v) : lohalf(v);
    };

    // one skewed step, issue-early/consume-late
    auto full_step = [&](float xpm) {
        // ---- L0 dot: a = xpm + wh0 . h1(tau-1)  (10 pk_fma) ----
        v2f aE = (v2f){xpm, 0.f}, aO = (v2f){0.f, 0.f};
        #pragma unroll
        for (int k = 0; k < H_ / 2; k += 2) {
            aE = pkfma(h1p[k],     wh0p[k],     aE);
            aO = pkfma(h1p[k + 1], wh0p[k + 1], aO);
        }
        v2f as = aE + aO;
        float h1n = fast_tanh(as.x + as.y);

        // ---- h1 exchange: write, then read back IMMEDIATELY (issue-early) ----
        h1s[slc][i] = h1n;
        v4f h1r[H_ / 4];
        #pragma unroll
        for (int k = 0; k < H_ / 4; ++k)
            h1r[k] = reinterpret_cast<const v4f*>(&h1s[slc][0])[k];

        // ---- L1 dots (skewed; OLD h1p/h2p regs) cover the h1-read latency ----
        v2f bE = (v2f){bias1, 0.f}, bO = (v2f){0.f, 0.f};
        #pragma unroll
        for (int k = 0; k < H_ / 2; k += 2) {
            bE = pkfma(h1p[k],     wi1p[k],     bE);
            bO = pkfma(h1p[k + 1], wi1p[k + 1], bO);
        }
        #pragma unroll
        for (int k = 0; k < H_ / 2; k += 2) {
            bE = pkfma(h2p[k],     wh1p[k],     bE);
            bO = pkfma(h2p[k + 1], wh1p[k + 1], bO);
        }
        v2f bs = bE + bO;
        float h2n = fast_tanh(bs.x + bs.y);

        // ---- h2 exchange: write + read; latency covered by next step's L0 ----
        h2s[slc][i] = h2n;
        v4f h2r[H_ / 4];
        #pragma unroll
        for (int k = 0; k < H_ / 4; ++k)
            h2r[k] = reinterpret_cast<const v4f*>(&h2s[slc][0])[k];

        // ---- commit (subregister renames, no instructions) ----
        #pragma unroll
        for (int k = 0; k < H_ / 4; ++k) {
            h1p[2*k] = lohalf(h1r[k]); h1p[2*k+1] = hihalf(h1r[k]);
            h2p[2*k] = lohalf(h2r[k]); h2p[2*k+1] = hihalf(h2r[k]);
        }
    };

    // consume xv -> xp for a chunk (5 pk_fma + add per step)
    auto consume_xp = [&](float (&xp)[CH]) {
        #pragma unroll
        for (int m = 0; m < CH; ++m) {
            v2f acc = (v2f){bias0, 0.f};
            #pragma unroll
            for (int q = 0; q < DIN / 2; ++q)
                acc = pkfma(getpair(m * (DIN / 2) + q), wi0p[q], acc);
            xp[m] = acc.x + acc.y;
        }
    };

    // ---- chunk 0 (tau = 0..CH-1), tau=0 peeled: h1(0)=tanh(xp[0]), no h2 update ----
    {
        float xp[CH];
        consume_xp(xp);
        #pragma unroll
        for (int k = 0; k < XV; ++k) xv[k] = xb[(CH * DIN) / 4 + k];  // prefetch chunk 1

        float h1n = fast_tanh(xp[0]);
        h1s[slc][i] = h1n;
        #pragma unroll
        for (int k = 0; k < H_ / 4; ++k) {
            v4f v = reinterpret_cast<const v4f*>(&h1s[slc][0])[k];
            h1p[2*k] = lohalf(v); h1p[2*k+1] = hihalf(v);
        }

        #pragma unroll
        for (int m = 1; m < CH; ++m) full_step(xp[m]);
    }

    // ---- main loop: chunks t0 = CH .. T-CH ----
    for (int t0 = CH; t0 < T_; t0 += CH) {
        float xp[CH];
        consume_xp(xp);
        {
            const int t0n = (t0 + CH < T_) ? (t0 + CH) : 0;  // clamp, branchless
            #pragma unroll
            for (int k = 0; k < XV; ++k) xv[k] = xb[(t0n * DIN) / 4 + k];
        }
        #pragma unroll
        for (int m = 0; m < CH; ++m) full_step(xp[m]);
    }

    // ---- epilogue: h2(T-1) from h1(T-1) (=h1p) and h2(T-2) (=h2p) ----
    {
        v2f bE = (v2f){bias1, 0.f}, bO = (v2f){0.f, 0.f};
        #pragma unroll
        for (int k = 0; k < H_ / 2; k += 2) {
            bE = pkfma(h1p[k],     wi1p[k],     bE);
            bO = pkfma(h1p[k + 1], wi1p[k + 1], bO);
        }
        #pragma unroll
        for (int k = 0; k < H_ / 2; k += 2) {
            bE = pkfma(h2p[k],     wh1p[k],     bE);
            bO = pkfma(h2p[k + 1], wh1p[k + 1], bO);
        }
        v2f bs = bE + bO;
        float h2n = fast_tanh(bs.x + bs.y);
        h2s[slc][i] = h2n;
        #pragma unroll
        for (int k = 0; k < H_ / 4; ++k) {
            v4f v = reinterpret_cast<const v4f*>(&h2s[slc][0])[k];
            h2p[2*k] = lohalf(v); h2p[2*k+1] = hihalf(v);
        }
    }

    // ---- FC: lanes i<2 hold full h2(T-1); out[samp][i] ----
    if (sl < SPW && samp < B_ && i < DOUT) {
        const v2f* fw = reinterpret_cast<const v2f*>(fc_w + i * H_);
        v2f acc = (v2f){fc_b[i], 0.f};
        #pragma unroll
        for (int k = 0; k < H_ / 2; ++k) acc = pkfma(h2p[k], fw[k], acc);
        out[samp * DOUT + i] = acc.x + acc.y;
    }
}

extern "C" void kernel_launch(void* const* d_in, const int* in_sizes, int n_in,
                              void* d_out, int out_size, void* d_ws, size_t ws_size,
                              hipStream_t stream) {
    (void)in_sizes; (void)n_in; (void)d_ws; (void)ws_size; (void)out_size;
    const float* x     = (const float*)d_in[0];
    const float* w_ih0 = (const float*)d_in[1];
    const float* w_hh0 = (const float*)d_in[2];
    const float* b_ih0 = (const float*)d_in[3];
    const float* b_hh0 = (const float*)d_in[4];
    const float* w_ih1 = (const float*)d_in[5];
    const float* w_hh1 = (const float*)d_in[6];
    const float* b_ih1 = (const float*)d_in[7];
    const float* b_hh1 = (const float*)d_in[8];
    const float* fc_w  = (const float*)d_in[9];
    const float* fc_b  = (const float*)d_in[10];
    float* out = (float*)d_out;

    const int grid = (B_ + SPW - 1) / SPW;   // 1366 single-wave blocks
    hipLaunchKernelGGL(rnn_pk2, dim3(grid), dim3(64), 0, stream,
                       x, w_ih0, w_hh0, b_ih0, b_hh0,
                       w_ih1, w_hh1, b_ih1, b_hh1, fc_w, fc_b, out);
}